// Round 3
// baseline (472.404 us; speedup 1.0000x reference)
//
#include <hip/hip_runtime.h>
#include <hip/hip_bf16.h>
#include <stdint.h>

// Problem constants (IMAGE_SIZES is compile-time constant in the reference)
#define K_DIM 4096          // D * MERGE^2
#define N_DIM 1024          // D
#define M_TOT 11955         // total merged blocks

#define BM 128
#define BN 128
#define BK 64
#define NWG_M 94            // ceil(11955/128)
#define NWG 752             // (N_DIM/BN) * NWG_M = 8*94, divisible by 8 XCDs

// Per-image tables: h = H/14, w = W/14; wm = w/2
__constant__ int c_wm[6]     = {44, 55, 45, 55, 32, 55};
__constant__ int c_w[6]      = {88, 110, 90, 110, 64, 110};
__constant__ int c_tokoff[6] = {0, 9680, 18480, 24240, 36340, 42100};
__constant__ int c_blkoff[6] = {0, 2420, 4620, 6060, 9085, 10525};

typedef __attribute__((ext_vector_type(8))) short bf16x8;
typedef __attribute__((ext_vector_type(4))) float f32x4;

// ---------------------------------------------------------------------------
// Weight fp32 -> bf16 with K-permutation k' = seg*1024 + d where original
// k = 4d + seg (seg = 2*kh + kw). Wp[n, seg*1024+d] = W[n, 4d+seg].
// Tiny pass: 16 MB read, 8 MB write.
// ---------------------------------------------------------------------------
__global__ __launch_bounds__(256) void wperm_cvt(
    const float* __restrict__ src, __hip_bfloat16* __restrict__ dst)
{
    const int n = blockIdx.x >> 1;
    const int t = (blockIdx.x & 1) * 256 + threadIdx.x;   // 0..511
    const float* row = src + (size_t)n * K_DIM + t * 8;
    float4 a = *(const float4*)row;        // k = 8t..8t+3  (d = 2t)
    float4 b = *(const float4*)(row + 4);  // k = 8t+4..8t+7 (d = 2t+1)
    const float va[8] = {a.x, a.y, a.z, a.w, b.x, b.y, b.z, b.w};
    __hip_bfloat16* drow = dst + (size_t)n * K_DIM + 2 * t;
#pragma unroll
    for (int seg = 0; seg < 4; ++seg) {
        __hip_bfloat162 h = __float22bfloat162_rn(
            make_float2(va[seg], va[4 + seg]));
        *(__hip_bfloat162*)(drow + seg * 1024) = h;
    }
}

// ---------------------------------------------------------------------------
// Fused GEMM: C[m,n] = sum_k' A'[m,k'] Wp[n,k'].
// A'[m, seg*1024+d] = feat[tok(m,seg)*1024 + d].
// A is staged into LDS as RAW FP32 via global_load_lds (fire-and-forget DMA,
// no VGPR round-trip — round 2's reg-staged cvt put the load latency on the
// critical path and cost +87 us). fp32->bf16 happens on the fragment-read
// path: 2x ds_read_b128 + 4x v_cvt_pk per fragment, overlappable with MFMA.
// B staged with global_load_lds (bf16, K-permuted by wperm_cvt).
// Swizzles (DMA dest linear, SOURCE pre-swizzled):
//   A: 16 chunks/row (256B), slot s holds global chunk g = s ^ (row&15)
//   B:  8 chunks/row (128B), slot p holds global chunk g = p ^ (row&7)
// Both are conflict-free per 8-lane group (low 3 slot bits distinct).
// 128x128 tile, BK=64, 4 waves (2x2 of 64x64), 16x16x32 bf16 MFMA.
// Grid: 1-D NWG with bijective XCD-chunked swizzle — all 8 N-tiles of one
// M-tile run on the SAME XCD so the A-tile is fetched into one L2 once.
// ---------------------------------------------------------------------------
__global__ __launch_bounds__(256) void gemm_fused(
    const float* __restrict__ A,            // feat fp32 [47820 x 1024]
    const __hip_bfloat16* __restrict__ Wp,  // permuted weight bf16 [1024 x 4096]
    float* __restrict__ C)
{
    __shared__ __align__(16) float lAf[BM * BK];           // 32 KB (fp32)
    __shared__ __align__(16) __hip_bfloat16 lB[BN * BK];   // 16 KB

    // ---- XCD-chunked swizzle (752 = 8*94, bijective)
    const int f    = blockIdx.x;
    const int xcd  = f & 7;
    const int slot = f >> 3;                 // 0..93
    const int gidx = xcd * NWG_M + slot;     // contiguous chunk per XCD
    const int mt   = gidx >> 3;              // 0..93
    const int nt   = gidx & 7;               // 0..7
    const int m0 = mt * BM;
    const int n0 = nt * BN;

    const int tid  = threadIdx.x;
    const int lane = tid & 63;
    const int wave = tid >> 6;
    const int wm = (wave >> 1) * 64;
    const int wn = (wave & 1) * 64;
    const int al = lane & 15;
    const int q  = lane >> 4;
    const int al7 = al & 7;

    // ---- A staging descriptors: 2048 fp32-chunks (16B), 8 per thread.
    // chunk c = tid + j*256: row = c>>4, slot = c&15 holds g = slot ^ (row&15)
    int tA00[8], wwA[8];
#pragma unroll
    for (int j = 0; j < 8; ++j) {
        const int c = tid + j * 256;
        const int row = c >> 4;
        const int g = (c & 15) ^ (row & 15);
        int gm = m0 + row; if (gm > M_TOT - 1) gm = M_TOT - 1;
        int img = 0;
#pragma unroll
        for (int u = 1; u < 6; ++u) if (gm >= c_blkoff[u]) img = u;
        const int bi = gm - c_blkoff[img];
        const int wmrg = c_wm[img];
        const int gi = bi / wmrg;
        const int gj = bi - gi * wmrg;
        const int w = c_w[img];
        tA00[j] = c_tokoff[img] + 2 * gi * w + 2 * gj;  // token of (kh,kw)=(0,0)
        wwA[j]  = w | (g << 16);
    }

    // ---- B staging descriptors: 1024 bf16-chunks (16B), 4 per thread.
    const __hip_bfloat16* pBbase[4];
#pragma unroll
    for (int j = 0; j < 4; ++j) {
        const int c = tid + j * 256;
        const int row = c >> 3;
        const int g = (c & 7) ^ (row & 7);
        pBbase[j] = Wp + (size_t)(n0 + row) * K_DIM + g * 8;
    }

    f32x4 acc[4][4];
#pragma unroll
    for (int i = 0; i < 4; ++i)
#pragma unroll
        for (int j = 0; j < 4; ++j)
            acc[i][j] = (f32x4){0.f, 0.f, 0.f, 0.f};

#pragma unroll
    for (int seg = 0; seg < 4; ++seg) {
        const int kh = seg >> 1, kw = seg & 1;
        const float* pA[8];
        const __hip_bfloat16* pB[4];
#pragma unroll
        for (int j = 0; j < 8; ++j) {
            const int w = wwA[j] & 0xffff;
            const int g = wwA[j] >> 16;
            pA[j] = A + (size_t)(tA00[j] + kh * w + kw) * N_DIM + g * 4;
        }
#pragma unroll
        for (int j = 0; j < 4; ++j)
            pB[j] = pBbase[j] + seg * 1024;

        for (int k2 = 0; k2 < 1024; k2 += BK) {
            // ---- B: async global->LDS DMA (4 x 16B per thread)
#pragma unroll
            for (int j = 0; j < 4; ++j)
                __builtin_amdgcn_global_load_lds(
                    (const __attribute__((address_space(1))) void*)(pB[j] + k2),
                    (__attribute__((address_space(3))) void*)(lB + (tid + j * 256) * 8),
                    16, 0, 0);
            // ---- A: async global->LDS DMA, raw fp32 (8 x 16B per thread)
#pragma unroll
            for (int j = 0; j < 8; ++j)
                __builtin_amdgcn_global_load_lds(
                    (const __attribute__((address_space(1))) void*)(pA[j] + k2),
                    (__attribute__((address_space(3))) void*)(lAf + (tid + j * 256) * 4),
                    16, 0, 0);
            __syncthreads();   // DMA drain (vmcnt) before fragment reads

            bf16x8 af[4], bfr[4];
#pragma unroll
            for (int ks = 0; ks < 2; ++ks) {
#pragma unroll
                for (int mi = 0; mi < 4; ++mi) {
                    const int r = wm + mi * 16 + al;
                    const int c0 = ks * 8 + q * 2;        // even fp32-chunk
                    const int r15 = r & 15;
                    const float4 ra0 = *(const float4*)(lAf + r * BK + (c0 ^ r15) * 4);
                    const float4 ra1 = *(const float4*)(lAf + r * BK + ((c0 + 1) ^ r15) * 4);
                    union { __hip_bfloat162 h2[4]; bf16x8 v; } pk;
                    pk.h2[0] = __float22bfloat162_rn(make_float2(ra0.x, ra0.y));
                    pk.h2[1] = __float22bfloat162_rn(make_float2(ra0.z, ra0.w));
                    pk.h2[2] = __float22bfloat162_rn(make_float2(ra1.x, ra1.y));
                    pk.h2[3] = __float22bfloat162_rn(make_float2(ra1.z, ra1.w));
                    af[mi] = pk.v;
                }
#pragma unroll
                for (int ni = 0; ni < 4; ++ni) {
                    const int r = wn + ni * 16 + al;
                    const int p = (ks * 4 + q) ^ al7;
                    bfr[ni] = *(const bf16x8*)(lB + r * BK + p * 8);
                }
#pragma unroll
                for (int mi = 0; mi < 4; ++mi)
#pragma unroll
                    for (int ni = 0; ni < 4; ++ni)
                        acc[mi][ni] = __builtin_amdgcn_mfma_f32_16x16x32_bf16(
                            af[mi], bfr[ni], acc[mi][ni], 0, 0, 0);
            }
            __syncthreads();   // reads done before next tile's DMA lands
        }
    }

    // C/D layout: col = lane&15, row = (lane>>4)*4 + reg
#pragma unroll
    for (int mi = 0; mi < 4; ++mi) {
        const int row = m0 + wm + mi * 16 + q * 4;
#pragma unroll
        for (int ni = 0; ni < 4; ++ni) {
            const int col = n0 + wn + ni * 16 + al;
            float* cp = C + (size_t)row * N_DIM + col;
#pragma unroll
            for (int rg = 0; rg < 4; ++rg) {
                if (row + rg < M_TOT) cp[(size_t)rg * N_DIM] = acc[mi][ni][rg];
            }
        }
    }
}

extern "C" void kernel_launch(void* const* d_in, const int* in_sizes, int n_in,
                              void* d_out, int out_size, void* d_ws, size_t ws_size,
                              hipStream_t stream)
{
    const float* feat = (const float*)d_in[0];
    const float* wgt  = (const float*)d_in[1];
    float* out = (float*)d_out;

    __hip_bfloat16* wp = (__hip_bfloat16*)d_ws;   // 8 MB permuted bf16 weight

    wperm_cvt<<<2048, 256, 0, stream>>>(wgt, wp);
    gemm_fused<<<NWG, 256, 0, stream>>>(feat, wp, out);
}